// Round 2
// baseline (3731.852 us; speedup 1.0000x reference)
//
#include <hip/hip_runtime.h>
#include <math.h>

#define D_MODEL 1024
#define N_HEADS 16
#define D_HEAD 64
#define D_FF 4096
#define NUM_FAM 64
#define DICT 4096
#define TOPK 8
#define BB 2
#define TT 2048
#define NTOK (BB*TT)

// output layout (floats): x[4194304] | attn[134217728] | fs[262144] | sp | e1 | e2
#define OUT_X    0L
#define OUT_ATTN 4194304L
#define OUT_FS   (OUT_ATTN + 134217728L)
#define OUT_SP   (OUT_FS + 262144L)
#define OUT_E1   (OUT_SP + 1L)
#define OUT_E2   (OUT_SP + 2L)

#define EPI_NONE 0
#define EPI_BASIS 1
#define EPI_ADD 2

// ---------------------------------------------------------------------------
// Generic tiled GEMM:  C = scale * (A @ op(B))  [+ epilogue]
//   A is [M,K] row-major (lda). If BTRANS: B is [N,K] (ldb) -> uses B^T.
//   else B is [K,N] (ldb). Batched via blockIdx.z with (b,h) strides, z = b*nzh+h.
//   EPI_NONE : C = scale*acc
//   EPI_ADD  : C = acc + X
//   EPI_BASIS: C = acc ; C2 = X - acc
// Tiles: 64x64, BK=16, 256 threads, 4x4 per thread. M,N multiples of 64, K of 16.
// ---------------------------------------------------------------------------
template<bool BTRANS, int EPI>
__global__ __launch_bounds__(256)
void gemm_k(const float* __restrict__ A, long lda, long sAb, long sAh,
            const float* __restrict__ B, long ldb, long sBb, long sBh,
            float* __restrict__ C, long ldc, long sCb, long sCh,
            const float* __restrict__ X, long ldx,
            float* __restrict__ C2,
            int K, int nzh, float scale)
{
    int z  = blockIdx.z;
    int zb = z / nzh, zh = z - zb * nzh;
    A += (long)zb * sAb + (long)zh * sAh;
    B += (long)zb * sBb + (long)zh * sBh;
    C += (long)zb * sCb + (long)zh * sCh;

    const long bm = (long)blockIdx.y * 64;
    const long bn = (long)blockIdx.x * 64;

    __shared__ float As[16][68];
    __shared__ float Bs[16][68];

    float acc[4][4] = {};

    const int tid = threadIdx.x;
    const int tx = tid & 15, ty = tid >> 4;
    const int lr = tid >> 2, lk = (tid & 3) * 4;   // A (and B^T) load: row, k-offset
    const int brow = tid >> 4, bc = (tid & 15) * 4; // B[K,N] load: k-row, col

    for (int k0 = 0; k0 < K; k0 += 16) {
        float4 a4 = *(const float4*)(A + (bm + lr) * lda + k0 + lk);
        As[lk + 0][lr] = a4.x; As[lk + 1][lr] = a4.y;
        As[lk + 2][lr] = a4.z; As[lk + 3][lr] = a4.w;
        if (BTRANS) {
            float4 b4 = *(const float4*)(B + (bn + lr) * ldb + k0 + lk);
            Bs[lk + 0][lr] = b4.x; Bs[lk + 1][lr] = b4.y;
            Bs[lk + 2][lr] = b4.z; Bs[lk + 3][lr] = b4.w;
        } else {
            float4 b4 = *(const float4*)(B + (long)(k0 + brow) * ldb + bn + bc);
            *(float4*)&Bs[brow][bc] = b4;
        }
        __syncthreads();
        #pragma unroll
        for (int kk = 0; kk < 16; kk++) {
            float4 av = *(const float4*)&As[kk][ty * 4];
            float4 bv = *(const float4*)&Bs[kk][tx * 4];
            acc[0][0] += av.x * bv.x; acc[0][1] += av.x * bv.y;
            acc[0][2] += av.x * bv.z; acc[0][3] += av.x * bv.w;
            acc[1][0] += av.y * bv.x; acc[1][1] += av.y * bv.y;
            acc[1][2] += av.y * bv.z; acc[1][3] += av.y * bv.w;
            acc[2][0] += av.z * bv.x; acc[2][1] += av.z * bv.y;
            acc[2][2] += av.z * bv.z; acc[2][3] += av.z * bv.w;
            acc[3][0] += av.w * bv.x; acc[3][1] += av.w * bv.y;
            acc[3][2] += av.w * bv.z; acc[3][3] += av.w * bv.w;
        }
        __syncthreads();
    }

    #pragma unroll
    for (int i = 0; i < 4; i++) {
        long r = bm + ty * 4 + i;
        #pragma unroll
        for (int j = 0; j < 4; j++) {
            long c = bn + tx * 4 + j;
            float v = acc[i][j];
            if (EPI == EPI_NONE) {
                C[r * ldc + c] = scale * v;
            } else if (EPI == EPI_ADD) {
                C[r * ldc + c] = v + X[r * ldx + c];
            } else { // EPI_BASIS
                C[r * ldc + c]  = v;
                C2[r * ldc + c] = X[r * ldx + c] - v;
            }
        }
    }
}

// Fused gate/up MLP GEMM: C = sigmoid(A@G^T) * silu(A@U^T), all [*,1024]@[4096,1024]^T
__global__ __launch_bounds__(256)
void gateup_k(const float* __restrict__ A, const float* __restrict__ G,
              const float* __restrict__ U, float* __restrict__ C)
{
    const long bm = (long)blockIdx.y * 64;
    const long bn = (long)blockIdx.x * 64;
    __shared__ float As[16][68];
    __shared__ float Gs[16][68];
    __shared__ float Us[16][68];
    float ag[4][4] = {}, au[4][4] = {};
    const int tid = threadIdx.x;
    const int tx = tid & 15, ty = tid >> 4;
    const int lr = tid >> 2, lk = (tid & 3) * 4;
    for (int k0 = 0; k0 < 1024; k0 += 16) {
        float4 a4 = *(const float4*)(A + (bm + lr) * 1024 + k0 + lk);
        As[lk + 0][lr] = a4.x; As[lk + 1][lr] = a4.y;
        As[lk + 2][lr] = a4.z; As[lk + 3][lr] = a4.w;
        float4 g4 = *(const float4*)(G + (bn + lr) * 1024 + k0 + lk);
        Gs[lk + 0][lr] = g4.x; Gs[lk + 1][lr] = g4.y;
        Gs[lk + 2][lr] = g4.z; Gs[lk + 3][lr] = g4.w;
        float4 u4 = *(const float4*)(U + (bn + lr) * 1024 + k0 + lk);
        Us[lk + 0][lr] = u4.x; Us[lk + 1][lr] = u4.y;
        Us[lk + 2][lr] = u4.z; Us[lk + 3][lr] = u4.w;
        __syncthreads();
        #pragma unroll
        for (int kk = 0; kk < 16; kk++) {
            float4 av = *(const float4*)&As[kk][ty * 4];
            float4 gv = *(const float4*)&Gs[kk][tx * 4];
            float4 uv = *(const float4*)&Us[kk][tx * 4];
            ag[0][0] += av.x * gv.x; ag[0][1] += av.x * gv.y; ag[0][2] += av.x * gv.z; ag[0][3] += av.x * gv.w;
            ag[1][0] += av.y * gv.x; ag[1][1] += av.y * gv.y; ag[1][2] += av.y * gv.z; ag[1][3] += av.y * gv.w;
            ag[2][0] += av.z * gv.x; ag[2][1] += av.z * gv.y; ag[2][2] += av.z * gv.z; ag[2][3] += av.z * gv.w;
            ag[3][0] += av.w * gv.x; ag[3][1] += av.w * gv.y; ag[3][2] += av.w * gv.z; ag[3][3] += av.w * gv.w;
            au[0][0] += av.x * uv.x; au[0][1] += av.x * uv.y; au[0][2] += av.x * uv.z; au[0][3] += av.x * uv.w;
            au[1][0] += av.y * uv.x; au[1][1] += av.y * uv.y; au[1][2] += av.y * uv.z; au[1][3] += av.y * uv.w;
            au[2][0] += av.z * uv.x; au[2][1] += av.z * uv.y; au[2][2] += av.z * uv.z; au[2][3] += av.z * uv.w;
            au[3][0] += av.w * uv.x; au[3][1] += av.w * uv.y; au[3][2] += av.w * uv.z; au[3][3] += av.w * uv.w;
        }
        __syncthreads();
    }
    #pragma unroll
    for (int i = 0; i < 4; i++) {
        long r = bm + ty * 4 + i;
        #pragma unroll
        for (int j = 0; j < 4; j++) {
            long c = bn + tx * 4 + j;
            float g = ag[i][j], u = au[i][j];
            float sg = 1.0f / (1.0f + expf(-g));
            float su = u / (1.0f + expf(-u));
            C[r * 4096 + c] = sg * su;
        }
    }
}

// Family softmax over 64 entries, in-place. One wave per token.
__global__ void fam_softmax_k(float* __restrict__ fs)
{
    long t = blockIdx.x;
    int lane = threadIdx.x;
    float v = fs[t * 64 + lane];
    float m = v;
    for (int off = 32; off; off >>= 1) m = fmaxf(m, __shfl_xor(m, off, 64));
    float e = expf(v - m);
    float s = e;
    for (int off = 32; off; off >>= 1) s += __shfl_xor(s, off, 64);
    fs[t * 64 + lane] = e / s;
}

// Top-8 per row of 4096 coeffs; accumulate sum(|vals|).
__global__ __launch_bounds__(256)
void topk_k(const float* __restrict__ coeffs, float* __restrict__ vals,
            int* __restrict__ idxs, float* __restrict__ sp_acc)
{
    __shared__ float sv[DICT];
    __shared__ float rmax[256];
    __shared__ int   ridx[256];
    long t = blockIdx.x;
    int tid = threadIdx.x;
    const float* row = coeffs + t * DICT;
    for (int i = tid; i < DICT; i += 256) sv[i] = row[i];
    __syncthreads();
    for (int j = 0; j < TOPK; j++) {
        float bm = -INFINITY; int bi = DICT;
        for (int i = tid; i < DICT; i += 256) {
            float v = sv[i];
            if (v > bm || (v == bm && i < bi)) { bm = v; bi = i; }
        }
        rmax[tid] = bm; ridx[tid] = bi;
        __syncthreads();
        for (int s = 128; s > 0; s >>= 1) {
            if (tid < s) {
                float o = rmax[tid + s]; int oi = ridx[tid + s];
                if (o > rmax[tid] || (o == rmax[tid] && oi < ridx[tid])) {
                    rmax[tid] = o; ridx[tid] = oi;
                }
            }
            __syncthreads();
        }
        if (tid == 0) {
            vals[t * TOPK + j] = rmax[0];
            idxs[t * TOPK + j] = ridx[0];
            sv[ridx[0]] = -INFINITY;
        }
        __syncthreads();
    }
    if (tid == 0) {
        float s = 0.f;
        for (int j = 0; j < TOPK; j++) s += fabsf(vals[t * TOPK + j]);
        atomicAdd(sp_acc, s);
    }
}

// x_recon = basis + sum_j vals[j]*dict[idx[j]] + bias
__global__ __launch_bounds__(256)
void recon_k(const float* __restrict__ basis, const float* __restrict__ vals,
             const int* __restrict__ idxs, const float* __restrict__ dictw,
             const float* __restrict__ bias, float* __restrict__ recon)
{
    long t = blockIdx.x;
    int tid = threadIdx.x;
    __shared__ float v8[TOPK];
    __shared__ int   i8[TOPK];
    if (tid < TOPK) { v8[tid] = vals[t * TOPK + tid]; i8[tid] = idxs[t * TOPK + tid]; }
    __syncthreads();
    int c = tid * 4;
    float4 acc = *(const float4*)(basis + t * D_MODEL + c);
    float4 bv  = *(const float4*)(bias + c);
    acc.x += bv.x; acc.y += bv.y; acc.z += bv.z; acc.w += bv.w;
    #pragma unroll
    for (int j = 0; j < TOPK; j++) {
        float4 dw = *(const float4*)(dictw + (long)i8[j] * D_MODEL + c);
        float vj = v8[j];
        acc.x += vj * dw.x; acc.y += vj * dw.y; acc.z += vj * dw.z; acc.w += vj * dw.w;
    }
    *(float4*)(recon + t * D_MODEL + c) = acc;
}

// RMSNorm per token: out = w*x/rms, rms = sqrt(mean(x^2)+eps); accumulate rms.
__global__ __launch_bounds__(256)
void rms_k(const float* __restrict__ in, const float* __restrict__ w,
           float* __restrict__ out, float* __restrict__ eacc)
{
    long t = blockIdx.x;
    int tid = threadIdx.x;
    float4 xv = *(const float4*)(in + t * D_MODEL + tid * 4);
    float ss = xv.x * xv.x + xv.y * xv.y + xv.z * xv.z + xv.w * xv.w;
    for (int off = 32; off; off >>= 1) ss += __shfl_down(ss, off, 64);
    __shared__ float sred[4];
    __shared__ float srms;
    int wid = tid >> 6, lane = tid & 63;
    if (lane == 0) sred[wid] = ss;
    __syncthreads();
    if (tid == 0) {
        float tot = sred[0] + sred[1] + sred[2] + sred[3];
        float rms = sqrtf(tot * (1.0f / D_MODEL) + 1e-6f);
        srms = rms;
        atomicAdd(eacc, rms);
    }
    __syncthreads();
    float rms = srms;
    float4 wv = *(const float4*)(w + tid * 4);
    float4 o;
    o.x = wv.x * xv.x / rms; o.y = wv.y * xv.y / rms;
    o.z = wv.z * xv.z / rms; o.w = wv.w * xv.w / rms;
    *(float4*)(out + t * D_MODEL + tid * 4) = o;
}

// Row softmax over 2048, in place. One block per row.
__global__ __launch_bounds__(256)
void attn_softmax_k(float* __restrict__ attn)
{
    long row = blockIdx.x;
    float* p = attn + row * (long)TT;
    int tid = threadIdx.x;
    float4 v0 = *(const float4*)(p + tid * 8);
    float4 v1 = *(const float4*)(p + tid * 8 + 4);
    float m = fmaxf(fmaxf(fmaxf(v0.x, v0.y), fmaxf(v0.z, v0.w)),
                    fmaxf(fmaxf(v1.x, v1.y), fmaxf(v1.z, v1.w)));
    for (int off = 32; off; off >>= 1) m = fmaxf(m, __shfl_xor(m, off, 64));
    __shared__ float sm[4];
    __shared__ float ssum[4];
    int wid = tid >> 6, lane = tid & 63;
    if (lane == 0) sm[wid] = m;
    __syncthreads();
    m = fmaxf(fmaxf(sm[0], sm[1]), fmaxf(sm[2], sm[3]));
    float e0 = expf(v0.x - m), e1 = expf(v0.y - m), e2 = expf(v0.z - m), e3 = expf(v0.w - m);
    float e4 = expf(v1.x - m), e5 = expf(v1.y - m), e6 = expf(v1.z - m), e7 = expf(v1.w - m);
    float s = e0 + e1 + e2 + e3 + e4 + e5 + e6 + e7;
    for (int off = 32; off; off >>= 1) s += __shfl_xor(s, off, 64);
    if (lane == 0) ssum[wid] = s;
    __syncthreads();
    s = ssum[0] + ssum[1] + ssum[2] + ssum[3];
    float4 o0, o1;
    o0.x = e0 / s; o0.y = e1 / s; o0.z = e2 / s; o0.w = e3 / s;
    o1.x = e4 / s; o1.y = e5 / s; o1.z = e6 / s; o1.w = e7 / s;
    *(float4*)(p + tid * 8) = o0;
    *(float4*)(p + tid * 8 + 4) = o1;
}

__global__ void init_k(float* acc)
{
    if (threadIdx.x < 3) acc[threadIdx.x] = 0.f;
}

__global__ void finalize_k(const float* __restrict__ acc, float* __restrict__ out)
{
    out[OUT_SP] = acc[0] / (float)((long)NTOK * DICT);
    out[OUT_E1] = acc[1] / (float)NTOK;
    out[OUT_E2] = acc[2] / (float)NTOK;
}

extern "C" void kernel_launch(void* const* d_in, const int* in_sizes, int n_in,
                              void* d_out, int out_size, void* d_ws, size_t ws_size,
                              hipStream_t stream)
{
    const float* x        = (const float*)d_in[0];
    const float* proto    = (const float*)d_in[1];
    const float* gate_w   = (const float*)d_in[2];
    const float* dict_w   = (const float*)d_in[3];
    const float* enc_w    = (const float*)d_in[4];
    const float* wq       = (const float*)d_in[5];
    const float* wk       = (const float*)d_in[6];
    const float* wv       = (const float*)d_in[7];
    const float* wo       = (const float*)d_in[8];
    const float* rel      = (const float*)d_in[9];
    const float* gproj    = (const float*)d_in[10];
    const float* uproj    = (const float*)d_in[11];
    const float* dproj    = (const float*)d_in[12];
    const float* norm1    = (const float*)d_in[13];
    const float* norm2    = (const float*)d_in[14];
    const float* bias     = (const float*)d_in[15];

    float* out = (float*)d_out;
    float* ws  = (float*)d_ws;

    // Workspace: 6 rotating 16MB units (4M floats each) + tiny tail = ~96.1MB.
    // Liveness overlay:
    //   U0: basis(3-6) -> kmod(9-10) -> normed2(14-15)
    //   U1: resid(3-4) -> recon(6-7) -> x2(13-16)
    //   U2: normed(7-8) -> attnout(12-13) -> hidden[0](15-16)
    //   U3: Q(8-10)                  -> hidden[1]
    //   U4: K(8-9)                   -> hidden[2]
    //   U5: V(8-12)                  -> hidden[3]
    // coeffs [4096,4096] lives in out.ATTN (scratch until step 10).
    const long M4 = 4194304L; // 4M floats = 16MB
    float* U0 = ws + 0 * M4;
    float* U1 = ws + 1 * M4;
    float* U2 = ws + 2 * M4;
    float* U3 = ws + 3 * M4;
    float* U4 = ws + 4 * M4;
    float* U5 = ws + 5 * M4;
    float* vals   = ws + 6 * M4;                     // 32768 floats
    int*   idxs   = (int*)(vals + NTOK * TOPK);      // 32768 ints
    float* accums = (float*)(idxs + NTOK * TOPK);    // 3 floats

    float* coeffs = out + OUT_ATTN;                  // scratch until step 10
    float* hidden = U2;                              // U2..U5 contiguous, 64MB

    dim3 B256(256);

    // 0. zero scalar accumulators
    init_k<<<dim3(1), dim3(64), 0, stream>>>(accums);

    // 1. family logits: x[4096,1024] @ gate_w[64,1024]^T -> out.FS
    gemm_k<true, EPI_NONE><<<dim3(1, 64, 1), B256, 0, stream>>>(
        x, 1024, 0, 0, gate_w, 1024, 0, 0, out + OUT_FS, 64, 0, 0,
        nullptr, 0, nullptr, 1024, 1, 1.0f);

    // 2. family softmax in-place
    fam_softmax_k<<<dim3(NTOK), dim3(64), 0, stream>>>(out + OUT_FS);

    // 3. basis = fs @ proto [64,1024] -> U0 ; resid = x - basis -> U1
    gemm_k<false, EPI_BASIS><<<dim3(16, 64, 1), B256, 0, stream>>>(
        out + OUT_FS, 64, 0, 0, proto, 1024, 0, 0, U0, 1024, 0, 0,
        x, 1024, U1, 64, 1, 1.0f);

    // 4. coeffs = resid @ enc_w^T -> out.ATTN scratch [4096,4096]
    gemm_k<true, EPI_NONE><<<dim3(64, 64, 1), B256, 0, stream>>>(
        U1, 1024, 0, 0, enc_w, 1024, 0, 0, coeffs, 4096, 0, 0,
        nullptr, 0, nullptr, 1024, 1, 1.0f);

    // 5. top-8 per token + sparsity accumulation
    topk_k<<<dim3(NTOK), B256, 0, stream>>>(coeffs, vals, idxs, accums + 0);

    // 6. x_recon = basis + sparse@dict + bias -> U1
    recon_k<<<dim3(NTOK), B256, 0, stream>>>(U0, vals, idxs, dict_w, bias, U1);

    // 7. normed = RMSNorm(x_recon, norm1) -> U2 ; accumulate rms into e1
    rms_k<<<dim3(NTOK), B256, 0, stream>>>(U1, norm1, U2, accums + 1);

    // 8. q,k,v projections -> U3, U4, U5
    gemm_k<true, EPI_NONE><<<dim3(16, 64, 1), B256, 0, stream>>>(
        U2, 1024, 0, 0, wq, 1024, 0, 0, U3, 1024, 0, 0,
        nullptr, 0, nullptr, 1024, 1, 1.0f);
    gemm_k<true, EPI_NONE><<<dim3(16, 64, 1), B256, 0, stream>>>(
        U2, 1024, 0, 0, wk, 1024, 0, 0, U4, 1024, 0, 0,
        nullptr, 0, nullptr, 1024, 1, 1.0f);
    gemm_k<true, EPI_NONE><<<dim3(16, 64, 1), B256, 0, stream>>>(
        U2, 1024, 0, 0, wv, 1024, 0, 0, U5, 1024, 0, 0,
        nullptr, 0, nullptr, 1024, 1, 1.0f);

    // 9. k_mod[t, h*64+e] = sum_d k[t,h*64+d] * rel[h,d,e] -> U0 (z = head)
    gemm_k<false, EPI_NONE><<<dim3(1, 64, 16), B256, 0, stream>>>(
        U4, 1024, 0, 64, rel, 64, 0, 4096, U0, 1024, 0, 64,
        nullptr, 0, nullptr, 64, 16, 1.0f);

    // 10. attn logits = 0.125 * q @ kmod^T  (z = b*16+h) -> out.ATTN
    gemm_k<true, EPI_NONE><<<dim3(32, 32, 32), B256, 0, stream>>>(
        U3, 1024, (long)TT * 1024, 64,
        U0, 1024, (long)TT * 1024, 64,
        out + OUT_ATTN, TT, 16L * TT * TT, (long)TT * TT,
        nullptr, 0, nullptr, 64, 16, 0.125f);

    // 11. softmax rows in-place (writes final attn output)
    attn_softmax_k<<<dim3(BB * N_HEADS * TT), B256, 0, stream>>>(out + OUT_ATTN);

    // 12. attnout[t, h*64+d] = attn @ v -> U2
    gemm_k<false, EPI_NONE><<<dim3(1, 32, 32), B256, 0, stream>>>(
        out + OUT_ATTN, TT, 16L * TT * TT, (long)TT * TT,
        U5, 1024, (long)TT * 1024, 64,
        U2, 1024, (long)TT * 1024, 64,
        nullptr, 0, nullptr, TT, 16, 1.0f);

    // 13. x2 = x + attnout @ wo^T -> U1
    gemm_k<true, EPI_ADD><<<dim3(16, 64, 1), B256, 0, stream>>>(
        U2, 1024, 0, 0, wo, 1024, 0, 0, U1, 1024, 0, 0,
        x, 1024, nullptr, 1024, 1, 1.0f);

    // 14. normed2 = RMSNorm(x2, norm2) -> U0 ; e2
    rms_k<<<dim3(NTOK), B256, 0, stream>>>(U1, norm2, U0, accums + 2);

    // 15. h = sigmoid(normed2@G^T) * silu(normed2@U^T) -> hidden (U2..U5)
    gateup_k<<<dim3(64, 64, 1), B256, 0, stream>>>(U0, gproj, uproj, hidden);

    // 16. x_out = x2 + h @ down^T -> out.X
    gemm_k<true, EPI_ADD><<<dim3(16, 64, 1), B256, 0, stream>>>(
        hidden, 4096, 0, 0, dproj, 4096, 0, 0, out + OUT_X, 1024, 0, 0,
        U1, 1024, nullptr, 4096, 1, 1.0f);

    // 17. scalars
    finalize_k<<<dim3(1), dim3(1), 0, stream>>>(accums, out);
}

// Round 5
// 2067.443 us; speedup vs baseline: 1.8051x; 1.8051x over previous
//
#include <hip/hip_runtime.h>
#include <math.h>

#define D_MODEL 1024
#define N_HEADS 16
#define D_HEAD 64
#define D_FF 4096
#define NUM_FAM 64
#define DICT 4096
#define TOPK 8
#define BB 2
#define TT 2048
#define NTOK (BB*TT)

// output layout (floats): x[4194304] | attn[134217728] | fs[262144] | sp | e1 | e2
#define OUT_X    0L
#define OUT_ATTN 4194304L
#define OUT_FS   (OUT_ATTN + 134217728L)
#define OUT_SP   (OUT_FS + 262144L)
#define OUT_E1   (OUT_SP + 1L)
#define OUT_E2   (OUT_SP + 2L)

#define EPI_NONE 0
#define EPI_BASIS 1
#define EPI_ADD 2

typedef unsigned short u16x8 __attribute__((ext_vector_type(8)));
typedef short          s16x8 __attribute__((ext_vector_type(8)));
typedef float          f32x4 __attribute__((ext_vector_type(4)));

__device__ __forceinline__ ushort f2b(float f) {
    unsigned u = __builtin_bit_cast(unsigned, f);
    unsigned r = (u + 0x7FFFu + ((u >> 16) & 1u)) >> 16;   // RNE
    return (ushort)r;
}

// ---------------------------------------------------------------------------
// fp32 tiled GEMM (kept for fam logits / basis / coeffs — top-k sensitivity)
// ---------------------------------------------------------------------------
template<bool BTRANS, int EPI>
__global__ __launch_bounds__(256)
void gemm_k(const float* __restrict__ A, long lda, long sAb, long sAh,
            const float* __restrict__ B, long ldb, long sBb, long sBh,
            float* __restrict__ C, long ldc, long sCb, long sCh,
            const float* __restrict__ X, long ldx,
            float* __restrict__ C2,
            int K, int nzh, float scale)
{
    int z  = blockIdx.z;
    int zb = z / nzh, zh = z - zb * nzh;
    A += (long)zb * sAb + (long)zh * sAh;
    B += (long)zb * sBb + (long)zh * sBh;
    C += (long)zb * sCb + (long)zh * sCh;

    const long bm = (long)blockIdx.y * 64;
    const long bn = (long)blockIdx.x * 64;

    __shared__ float As[16][68];
    __shared__ float Bs[16][68];

    float acc[4][4] = {};

    const int tid = threadIdx.x;
    const int tx = tid & 15, ty = tid >> 4;
    const int lr = tid >> 2, lk = (tid & 3) * 4;
    const int brow = tid >> 4, bc = (tid & 15) * 4;

    for (int k0 = 0; k0 < K; k0 += 16) {
        float4 a4 = *(const float4*)(A + (bm + lr) * lda + k0 + lk);
        As[lk + 0][lr] = a4.x; As[lk + 1][lr] = a4.y;
        As[lk + 2][lr] = a4.z; As[lk + 3][lr] = a4.w;
        if (BTRANS) {
            float4 b4 = *(const float4*)(B + (bn + lr) * ldb + k0 + lk);
            Bs[lk + 0][lr] = b4.x; Bs[lk + 1][lr] = b4.y;
            Bs[lk + 2][lr] = b4.z; Bs[lk + 3][lr] = b4.w;
        } else {
            float4 b4 = *(const float4*)(B + (long)(k0 + brow) * ldb + bn + bc);
            *(float4*)&Bs[brow][bc] = b4;
        }
        __syncthreads();
        #pragma unroll
        for (int kk = 0; kk < 16; kk++) {
            float4 av = *(const float4*)&As[kk][ty * 4];
            float4 bv = *(const float4*)&Bs[kk][tx * 4];
            acc[0][0] += av.x * bv.x; acc[0][1] += av.x * bv.y;
            acc[0][2] += av.x * bv.z; acc[0][3] += av.x * bv.w;
            acc[1][0] += av.y * bv.x; acc[1][1] += av.y * bv.y;
            acc[1][2] += av.y * bv.z; acc[1][3] += av.y * bv.w;
            acc[2][0] += av.z * bv.x; acc[2][1] += av.z * bv.y;
            acc[2][2] += av.z * bv.z; acc[2][3] += av.z * bv.w;
            acc[3][0] += av.w * bv.x; acc[3][1] += av.w * bv.y;
            acc[3][2] += av.w * bv.z; acc[3][3] += av.w * bv.w;
        }
        __syncthreads();
    }

    #pragma unroll
    for (int i = 0; i < 4; i++) {
        long r = bm + ty * 4 + i;
        #pragma unroll
        for (int j = 0; j < 4; j++) {
            long c = bn + tx * 4 + j;
            float v = acc[i][j];
            if (EPI == EPI_NONE) {
                C[r * ldc + c] = scale * v;
            } else if (EPI == EPI_ADD) {
                C[r * ldc + c] = v + X[r * ldx + c];
            } else { // EPI_BASIS
                C[r * ldc + c]  = v;
                C2[r * ldc + c] = X[r * ldx + c] - v;
            }
        }
    }
}

// ---------------------------------------------------------------------------
// bf16 MFMA GEMM:  C = scale * (A @ B^T)   A:[M,K]  B:[N,K] bf16 (ushort)
//   config A: WGM=2,WGN=2,FM=4,FN=4 -> 128x128 tile
//   config B: WGM=4,WGN=1,FM=2,FN=4 -> 128x64 tile
//   AIN: 0 = A bf16, 1 = A fp32 (convert while staging)
//   EPI: 0 = f32*scale, 1 = bf16, 2 = f32 acc + X
// LDS tiles [rows][32k] bf16, chunk-XOR swizzle (phys = logical ^ ((row>>1)&3))
// -> 2-way bank aliasing on ds_read_b128 (free, m136).
// ---------------------------------------------------------------------------
template<int WGM, int WGN, int FM, int FN, int AIN, int EPI>
__global__ __launch_bounds__(256)
void mgemm_k(const void* __restrict__ Ap, long lda, long sAb, long sAh,
             const ushort* __restrict__ Bp, long ldb, long sBb, long sBh,
             void* __restrict__ Cp, long ldc, long sCb, long sCh,
             const float* __restrict__ X, long ldx,
             long K, int nzh, float scale)
{
    constexpr int BM = WGM * FM * 16;
    constexpr int BN = WGN * FN * 16;
    constexpr int NCA = (BM * 4) / 256;
    constexpr int NCB = (BN * 4) / 256;
    __shared__ ushort Asm[BM * 32];
    __shared__ ushort Bsm[BN * 32];

    const int tid = threadIdx.x;
    const int lane = tid & 63;
    const int wid = tid >> 6;
    const int wr = wid / WGN, wc = wid % WGN;

    int z = blockIdx.z;
    int zb = z / nzh, zh = z - zb * nzh;
    long zoff = (long)zb * sAb + (long)zh * sAh;
    const ushort* Ab = (const ushort*)Ap + (AIN == 0 ? zoff : 0);
    const float*  Af = (const float*)Ap  + (AIN == 1 ? zoff : 0);
    const ushort* Bb = Bp + (long)zb * sBb + (long)zh * sBh;
    float*  Cf = (float*)Cp  + (long)zb * sCb + (long)zh * sCh;
    ushort* Cb = (ushort*)Cp + (long)zb * sCb + (long)zh * sCh;

    const long bm = (long)blockIdx.y * BM;
    const long bn = (long)blockIdx.x * BN;

    f32x4 acc[FM][FN] = {};

    for (long k0 = 0; k0 < K; k0 += 32) {
        u16x8 ra[NCA], rb[NCB];
        #pragma unroll
        for (int i = 0; i < NCA; i++) {
            int c = i * 256 + tid, row = c >> 2, lc = c & 3;
            if (AIN == 0) {
                ra[i] = *(const u16x8*)(Ab + (bm + row) * lda + k0 + lc * 8);
            } else {
                const float* p = Af + (bm + row) * lda + k0 + lc * 8;
                float4 f0 = *(const float4*)p;
                float4 f1 = *(const float4*)(p + 4);
                u16x8 t;
                t[0]=f2b(f0.x); t[1]=f2b(f0.y); t[2]=f2b(f0.z); t[3]=f2b(f0.w);
                t[4]=f2b(f1.x); t[5]=f2b(f1.y); t[6]=f2b(f1.z); t[7]=f2b(f1.w);
                ra[i] = t;
            }
        }
        #pragma unroll
        for (int i = 0; i < NCB; i++) {
            int c = i * 256 + tid, row = c >> 2, lc = c & 3;
            rb[i] = *(const u16x8*)(Bb + (bn + row) * ldb + k0 + lc * 8);
        }
        __syncthreads();   // prior iter's LDS reads complete
        #pragma unroll
        for (int i = 0; i < NCA; i++) {
            int c = i * 256 + tid, row = c >> 2;
            int pc = (c & 3) ^ ((row >> 1) & 3);
            *(u16x8*)&Asm[row * 32 + pc * 8] = ra[i];
        }
        #pragma unroll
        for (int i = 0; i < NCB; i++) {
            int c = i * 256 + tid, row = c >> 2;
            int pc = (c & 3) ^ ((row >> 1) & 3);
            *(u16x8*)&Bsm[row * 32 + pc * 8] = rb[i];
        }
        __syncthreads();
        s16x8 af[FM], bf[FN];
        #pragma unroll
        for (int m = 0; m < FM; m++) {
            int row = wr * FM * 16 + m * 16 + (lane & 15);
            int ph = (lane >> 4) ^ ((row >> 1) & 3);
            af[m] = *(const s16x8*)&Asm[row * 32 + ph * 8];
        }
        #pragma unroll
        for (int n = 0; n < FN; n++) {
            int row = wc * FN * 16 + n * 16 + (lane & 15);
            int ph = (lane >> 4) ^ ((row >> 1) & 3);
            bf[n] = *(const s16x8*)&Bsm[row * 32 + ph * 8];
        }
        #pragma unroll
        for (int m = 0; m < FM; m++)
            #pragma unroll
            for (int n = 0; n < FN; n++)
                acc[m][n] = __builtin_amdgcn_mfma_f32_16x16x32_bf16(af[m], bf[n], acc[m][n], 0, 0, 0);
    }

    // epilogue: C/D layout col=lane&15, row=(lane>>4)*4+reg  [m89/m91]
    #pragma unroll
    for (int m = 0; m < FM; m++) {
        #pragma unroll
        for (int n = 0; n < FN; n++) {
            long row0 = bm + wr * FM * 16 + m * 16 + (lane >> 4) * 4;
            long col  = bn + wc * FN * 16 + n * 16 + (lane & 15);
            #pragma unroll
            for (int r = 0; r < 4; r++) {
                float v = acc[m][n][r];
                if (EPI == 0)      Cf[(row0 + r) * ldc + col] = v * scale;
                else if (EPI == 1) Cb[(row0 + r) * ldc + col] = f2b(v);
                else               Cf[(row0 + r) * ldc + col] = v + X[(row0 + r) * ldx + col];
            }
        }
    }
}

// ---------------------------------------------------------------------------
// Fused gate/up MFMA GEMM: H = bf16( sigmoid(A@G^T) * silu(A@U^T) )
// 128x64 tile (WGM=4, FM=2, FN=4), dual B operand. M=N=4096, K=1024.
// ---------------------------------------------------------------------------
__global__ __launch_bounds__(256)
void mgateup_k(const ushort* __restrict__ A, const ushort* __restrict__ G,
               const ushort* __restrict__ U, ushort* __restrict__ H)
{
    __shared__ ushort Asm[128 * 32];
    __shared__ ushort Gsm[64 * 32];
    __shared__ ushort Usm[64 * 32];

    const int tid = threadIdx.x;
    const int lane = tid & 63;
    const int wid = tid >> 6;
    const long bm = (long)blockIdx.y * 128;
    const long bn = (long)blockIdx.x * 64;

    f32x4 ag[2][4] = {};
    f32x4 au[2][4] = {};

    for (long k0 = 0; k0 < 1024; k0 += 32) {
        u16x8 ra[2], rg, ru;
        #pragma unroll
        for (int i = 0; i < 2; i++) {
            int c = i * 256 + tid, row = c >> 2, lc = c & 3;
            ra[i] = *(const u16x8*)(A + (bm + row) * 1024 + k0 + lc * 8);
        }
        {
            int row = tid >> 2, lc = tid & 3;
            rg = *(const u16x8*)(G + (bn + row) * 1024 + k0 + lc * 8);
            ru = *(const u16x8*)(U + (bn + row) * 1024 + k0 + lc * 8);
        }
        __syncthreads();
        #pragma unroll
        for (int i = 0; i < 2; i++) {
            int c = i * 256 + tid, row = c >> 2;
            int pc = (c & 3) ^ ((row >> 1) & 3);
            *(u16x8*)&Asm[row * 32 + pc * 8] = ra[i];
        }
        {
            int row = tid >> 2;
            int pc = (tid & 3) ^ ((row >> 1) & 3);
            *(u16x8*)&Gsm[row * 32 + pc * 8] = rg;
            *(u16x8*)&Usm[row * 32 + pc * 8] = ru;
        }
        __syncthreads();
        s16x8 af[2], gf[4], uf[4];
        #pragma unroll
        for (int m = 0; m < 2; m++) {
            int row = wid * 32 + m * 16 + (lane & 15);
            int ph = (lane >> 4) ^ ((row >> 1) & 3);
            af[m] = *(const s16x8*)&Asm[row * 32 + ph * 8];
        }
        #pragma unroll
        for (int n = 0; n < 4; n++) {
            int row = n * 16 + (lane & 15);
            int ph = (lane >> 4) ^ ((row >> 1) & 3);
            gf[n] = *(const s16x8*)&Gsm[row * 32 + ph * 8];
            uf[n] = *(const s16x8*)&Usm[row * 32 + ph * 8];
        }
        #pragma unroll
        for (int m = 0; m < 2; m++)
            #pragma unroll
            for (int n = 0; n < 4; n++) {
                ag[m][n] = __builtin_amdgcn_mfma_f32_16x16x32_bf16(af[m], gf[n], ag[m][n], 0, 0, 0);
                au[m][n] = __builtin_amdgcn_mfma_f32_16x16x32_bf16(af[m], uf[n], au[m][n], 0, 0, 0);
            }
    }

    #pragma unroll
    for (int m = 0; m < 2; m++) {
        #pragma unroll
        for (int n = 0; n < 4; n++) {
            long row0 = bm + wid * 32 + m * 16 + (lane >> 4) * 4;
            long col  = bn + n * 16 + (lane & 15);
            #pragma unroll
            for (int r = 0; r < 4; r++) {
                float g = ag[m][n][r], u = au[m][n][r];
                float sg = 1.0f / (1.0f + expf(-g));
                float su = u / (1.0f + expf(-u));
                H[(row0 + r) * 4096 + col] = f2b(sg * su);
            }
        }
    }
}

// ---------------------------------------------------------------------------
// small kernels
// ---------------------------------------------------------------------------
__global__ void fam_softmax_k(float* __restrict__ fs)
{
    long t = blockIdx.x;
    int lane = threadIdx.x;
    float v = fs[t * 64 + lane];
    float m = v;
    for (int off = 32; off; off >>= 1) m = fmaxf(m, __shfl_xor(m, off, 64));
    float e = expf(v - m);
    float s = e;
    for (int off = 32; off; off >>= 1) s += __shfl_xor(s, off, 64);
    fs[t * 64 + lane] = e / s;
}

__global__ __launch_bounds__(256)
void topk_k(const float* __restrict__ coeffs, float* __restrict__ vals,
            int* __restrict__ idxs, float* __restrict__ sp_acc)
{
    __shared__ float sv[DICT];
    __shared__ float rmax[256];
    __shared__ int   ridx[256];
    long t = blockIdx.x;
    int tid = threadIdx.x;
    const float* row = coeffs + t * DICT;
    for (int i = tid; i < DICT; i += 256) sv[i] = row[i];
    __syncthreads();
    for (int j = 0; j < TOPK; j++) {
        float bm = -INFINITY; int bi = DICT;
        for (int i = tid; i < DICT; i += 256) {
            float v = sv[i];
            if (v > bm || (v == bm && i < bi)) { bm = v; bi = i; }
        }
        rmax[tid] = bm; ridx[tid] = bi;
        __syncthreads();
        for (int s = 128; s > 0; s >>= 1) {
            if (tid < s) {
                float o = rmax[tid + s]; int oi = ridx[tid + s];
                if (o > rmax[tid] || (o == rmax[tid] && oi < ridx[tid])) {
                    rmax[tid] = o; ridx[tid] = oi;
                }
            }
            __syncthreads();
        }
        if (tid == 0) {
            vals[t * TOPK + j] = rmax[0];
            idxs[t * TOPK + j] = ridx[0];
            sv[ridx[0]] = -INFINITY;
        }
        __syncthreads();
    }
    if (tid == 0) {
        float s = 0.f;
        for (int j = 0; j < TOPK; j++) s += fabsf(vals[t * TOPK + j]);
        atomicAdd(sp_acc, s);
    }
}

__global__ __launch_bounds__(256)
void recon_k(const float* __restrict__ basis, const float* __restrict__ vals,
             const int* __restrict__ idxs, const float* __restrict__ dictw,
             const float* __restrict__ bias, float* __restrict__ recon)
{
    long t = blockIdx.x;
    int tid = threadIdx.x;
    __shared__ float v8[TOPK];
    __shared__ int   i8[TOPK];
    if (tid < TOPK) { v8[tid] = vals[t * TOPK + tid]; i8[tid] = idxs[t * TOPK + tid]; }
    __syncthreads();
    int c = tid * 4;
    float4 acc = *(const float4*)(basis + t * D_MODEL + c);
    float4 bv  = *(const float4*)(bias + c);
    acc.x += bv.x; acc.y += bv.y; acc.z += bv.z; acc.w += bv.w;
    #pragma unroll
    for (int j = 0; j < TOPK; j++) {
        float4 dw = *(const float4*)(dictw + (long)i8[j] * D_MODEL + c);
        float vj = v8[j];
        acc.x += vj * dw.x; acc.y += vj * dw.y; acc.z += vj * dw.z; acc.w += vj * dw.w;
    }
    *(float4*)(recon + t * D_MODEL + c) = acc;
}

// RMSNorm -> bf16 out; accumulates rms into eacc.
__global__ __launch_bounds__(256)
void rms_k(const float* __restrict__ in, const float* __restrict__ w,
           ushort* __restrict__ outb, float* __restrict__ eacc)
{
    long t = blockIdx.x;
    int tid = threadIdx.x;
    float4 xv = *(const float4*)(in + t * D_MODEL + tid * 4);
    float ss = xv.x * xv.x + xv.y * xv.y + xv.z * xv.z + xv.w * xv.w;
    for (int off = 32; off; off >>= 1) ss += __shfl_down(ss, off, 64);
    __shared__ float sred[4];
    __shared__ float srms;
    int wid = tid >> 6, lane = tid & 63;
    if (lane == 0) sred[wid] = ss;
    __syncthreads();
    if (tid == 0) {
        float tot = sred[0] + sred[1] + sred[2] + sred[3];
        float rms = sqrtf(tot * (1.0f / D_MODEL) + 1e-6f);
        srms = rms;
        atomicAdd(eacc, rms);
    }
    __syncthreads();
    float rms = srms;
    float4 wv = *(const float4*)(w + tid * 4);
    ushort4 o;
    o.x = f2b(wv.x * xv.x / rms); o.y = f2b(wv.y * xv.y / rms);
    o.z = f2b(wv.z * xv.z / rms); o.w = f2b(wv.w * xv.w / rms);
    *(ushort4*)(outb + t * D_MODEL + tid * 4) = o;
}

__global__ __launch_bounds__(256)
void attn_softmax_k(float* __restrict__ attn)
{
    long row = blockIdx.x;
    float* p = attn + row * (long)TT;
    int tid = threadIdx.x;
    float4 v0 = *(const float4*)(p + tid * 8);
    float4 v1 = *(const float4*)(p + tid * 8 + 4);
    float m = fmaxf(fmaxf(fmaxf(v0.x, v0.y), fmaxf(v0.z, v0.w)),
                    fmaxf(fmaxf(v1.x, v1.y), fmaxf(v1.z, v1.w)));
    for (int off = 32; off; off >>= 1) m = fmaxf(m, __shfl_xor(m, off, 64));
    __shared__ float sm[4];
    __shared__ float ssum[4];
    int wid = tid >> 6, lane = tid & 63;
    if (lane == 0) sm[wid] = m;
    __syncthreads();
    m = fmaxf(fmaxf(sm[0], sm[1]), fmaxf(sm[2], sm[3]));
    float e0 = expf(v0.x - m), e1 = expf(v0.y - m), e2 = expf(v0.z - m), e3 = expf(v0.w - m);
    float e4 = expf(v1.x - m), e5 = expf(v1.y - m), e6 = expf(v1.z - m), e7 = expf(v1.w - m);
    float s = e0 + e1 + e2 + e3 + e4 + e5 + e6 + e7;
    for (int off = 32; off; off >>= 1) s += __shfl_xor(s, off, 64);
    if (lane == 0) ssum[wid] = s;
    __syncthreads();
    s = ssum[0] + ssum[1] + ssum[2] + ssum[3];
    float4 o0, o1;
    o0.x = e0 / s; o0.y = e1 / s; o0.z = e2 / s; o0.w = e3 / s;
    o1.x = e4 / s; o1.y = e5 / s; o1.z = e6 / s; o1.w = e7 / s;
    *(float4*)(p + tid * 8) = o0;
    *(float4*)(p + tid * 8 + 4) = o1;
}

// weight fp32 -> bf16: z selects tensor {wq,wk,wv,wo (1M), g,u,d (4M)}
__global__ __launch_bounds__(256)
void wconv_k(const float* __restrict__ s0, const float* __restrict__ s1,
             const float* __restrict__ s2, const float* __restrict__ s3,
             const float* __restrict__ s4, const float* __restrict__ s5,
             const float* __restrict__ s6,
             ushort* __restrict__ d0, ushort* __restrict__ d1,
             ushort* __restrict__ d2, ushort* __restrict__ d3,
             ushort* __restrict__ d4, ushort* __restrict__ d5,
             ushort* __restrict__ d6)
{
    int zi = blockIdx.z;
    const float* s; ushort* d; long n;
    switch (zi) {
        case 0: s = s0; d = d0; n = 1048576; break;
        case 1: s = s1; d = d1; n = 1048576; break;
        case 2: s = s2; d = d2; n = 1048576; break;
        case 3: s = s3; d = d3; n = 1048576; break;
        case 4: s = s4; d = d4; n = 4194304; break;
        case 5: s = s5; d = d5; n = 4194304; break;
        default: s = s6; d = d6; n = 4194304; break;
    }
    long i = ((long)blockIdx.x * 256 + threadIdx.x) * 8;
    if (i >= n) return;
    float4 f0 = *(const float4*)(s + i);
    float4 f1 = *(const float4*)(s + i + 4);
    u16x8 t;
    t[0]=f2b(f0.x); t[1]=f2b(f0.y); t[2]=f2b(f0.z); t[3]=f2b(f0.w);
    t[4]=f2b(f1.x); t[5]=f2b(f1.y); t[6]=f2b(f1.z); t[7]=f2b(f1.w);
    *(u16x8*)(d + i) = t;
}

// rel [16][64 d][64 e] fp32 -> relT bf16 [16][64 e][64 d]
__global__ void relt_k(const float* __restrict__ rel, ushort* __restrict__ relT)
{
    int h = blockIdx.x;
    int tid = threadIdx.x;
    for (int i = tid; i < 4096; i += 256) {
        int d = i >> 6, e = i & 63;
        relT[h * 4096 + e * 64 + d] = f2b(rel[h * 4096 + d * 64 + e]);
    }
}

// v bf16 [4096][1024] -> vT bf16 [32 z][64 d][2048 k]
__global__ __launch_bounds__(256)
void vtrans_k(const ushort* __restrict__ v, ushort* __restrict__ vT)
{
    __shared__ ushort t[64][72];
    int z = blockIdx.y; int b = z >> 4, h = z & 15;
    long k0 = (long)blockIdx.x * 64;
    int tid = threadIdx.x;
    int kr = tid >> 2, c0 = (tid & 3) * 16;
    const ushort* src = v + (b * 2048L + k0 + kr) * 1024 + h * 64 + c0;
    u16x8 a = *(const u16x8*)src;
    u16x8 bb = *(const u16x8*)(src + 8);
    #pragma unroll
    for (int j = 0; j < 8; j++) t[c0 + j][kr] = a[j];
    #pragma unroll
    for (int j = 0; j < 8; j++) t[c0 + 8 + j][kr] = bb[j];
    __syncthreads();
    int dr = tid >> 2, kc0 = (tid & 3) * 16;
    u16x8 o0, o1;
    #pragma unroll
    for (int j = 0; j < 8; j++) { o0[j] = t[dr][kc0 + j]; o1[j] = t[dr][kc0 + 8 + j]; }
    ushort* dst = vT + (long)z * 131072 + (long)dr * 2048 + k0 + kc0;
    *(u16x8*)dst = o0;
    *(u16x8*)(dst + 8) = o1;
}

__global__ void init_k(float* acc)
{
    if (threadIdx.x < 3) acc[threadIdx.x] = 0.f;
}

__global__ void finalize_k(const float* __restrict__ acc, float* __restrict__ out)
{
    out[OUT_SP] = acc[0] / (float)((long)NTOK * DICT);
    out[OUT_E1] = acc[1] / (float)NTOK;
    out[OUT_E2] = acc[2] / (float)NTOK;
}

extern "C" void kernel_launch(void* const* d_in, const int* in_sizes, int n_in,
                              void* d_out, int out_size, void* d_ws, size_t ws_size,
                              hipStream_t stream)
{
    const float* x      = (const float*)d_in[0];
    const float* proto  = (const float*)d_in[1];
    const float* gate_w = (const float*)d_in[2];
    const float* dict_w = (const float*)d_in[3];
    const float* enc_w  = (const float*)d_in[4];
    const float* wq     = (const float*)d_in[5];
    const float* wk     = (const float*)d_in[6];
    const float* wv     = (const float*)d_in[7];
    const float* wo     = (const float*)d_in[8];
    const float* rel    = (const float*)d_in[9];
    const float* gproj  = (const float*)d_in[10];
    const float* uproj  = (const float*)d_in[11];
    const float* dproj  = (const float*)d_in[12];
    const float* norm1  = (const float*)d_in[13];
    const float* norm2  = (const float*)d_in[14];
    const float* bias   = (const float*)d_in[15];

    float* out = (float*)d_out;

    // ---- workspace layout (~128.4 MB) ----
    const long M4 = 4194304L;
    float*  F0    = (float*)d_ws;            // basis -> x2
    float*  F1    = F0 + M4;                 // resid -> recon
    ushort* SP    = (ushort*)(F1 + M4);      // 8 bf16 slots of 4M elems
    ushort* S_normed  = SP + 0 * M4;         // -> hidden[0]
    ushort* S_q       = SP + 1 * M4;         // -> hidden[1]
    ushort* S_k       = SP + 2 * M4;         // -> hidden[2]
    ushort* S_kmod    = SP + 3 * M4;         // -> hidden[3]
    ushort* S_v       = SP + 4 * M4;         // -> attnout
    ushort* S_normed2 = SP + 5 * M4;
    ushort* S_vT      = SP + 6 * M4;         // 2 slots (16MB)
    ushort* hidden    = SP + 0 * M4;         // S0..S3 contiguous 32MB
    ushort* attnout   = SP + 4 * M4;
    ushort* WB    = SP + 8 * M4;             // bf16 weights
    ushort* wq_b  = WB + 0L * 1048576;
    ushort* wk_b  = WB + 1L * 1048576;
    ushort* wv_b  = WB + 2L * 1048576;
    ushort* wo_b  = WB + 3L * 1048576;
    ushort* g_b   = WB + 4L * 1048576;
    ushort* u_b   = WB + 8L * 1048576;
    ushort* d_b   = WB + 12L * 1048576;
    ushort* relT  = WB + 16L * 1048576;
    float*  vals  = (float*)(relT + 65536);
    int*    idxs  = (int*)(vals + (long)NTOK * TOPK);
    float*  accums= (float*)(idxs + (long)NTOK * TOPK);

    float* coeffs = out + OUT_ATTN;          // scratch until logits written

    dim3 B256(256);

    // 0. zero accumulators; convert weights
    init_k<<<dim3(1), dim3(64), 0, stream>>>(accums);
    wconv_k<<<dim3(2048, 1, 7), B256, 0, stream>>>(wq, wk, wv, wo, gproj, uproj, dproj,
                                                   wq_b, wk_b, wv_b, wo_b, g_b, u_b, d_b);
    relt_k<<<dim3(16), B256, 0, stream>>>(rel, relT);

    // 1-2. family logits (fp32) + softmax
    gemm_k<true, EPI_NONE><<<dim3(1, 64, 1), B256, 0, stream>>>(
        x, 1024, 0, 0, gate_w, 1024, 0, 0, out + OUT_FS, 64, 0, 0,
        nullptr, 0, nullptr, 1024, 1, 1.0f);
    fam_softmax_k<<<dim3(NTOK), dim3(64), 0, stream>>>(out + OUT_FS);

    // 3. basis (F0 fp32); resid = x - basis (F1 fp32)
    gemm_k<false, EPI_BASIS><<<dim3(16, 64, 1), B256, 0, stream>>>(
        out + OUT_FS, 64, 0, 0, proto, 1024, 0, 0, F0, 1024, 0, 0,
        x, 1024, F1, 64, 1, 1.0f);

    // 4. coeffs = resid @ enc^T (fp32 — top-k is discretely sensitive)
    gemm_k<true, EPI_NONE><<<dim3(64, 64, 1), B256, 0, stream>>>(
        F1, 1024, 0, 0, enc_w, 1024, 0, 0, coeffs, 4096, 0, 0,
        nullptr, 0, nullptr, 1024, 1, 1.0f);

    // 5-6. top-8 + recon (F1 fp32)
    topk_k<<<dim3(NTOK), B256, 0, stream>>>(coeffs, vals, idxs, accums + 0);
    recon_k<<<dim3(NTOK), B256, 0, stream>>>(F0, vals, idxs, dict_w, bias, F1);

    // 7. normed = RMSNorm(recon) -> bf16
    rms_k<<<dim3(NTOK), B256, 0, stream>>>(F1, norm1, S_normed, accums + 1);

    // 8. QKV (bf16 MFMA, 128x128)
    mgemm_k<2,2,4,4,0,1><<<dim3(8, 32, 1), B256, 0, stream>>>(
        S_normed, 1024, 0, 0, wq_b, 1024, 0, 0, S_q, 1024, 0, 0,
        nullptr, 0, 1024, 1, 1.0f);
    mgemm_k<2,2,4,4,0,1><<<dim3(8, 32, 1), B256, 0, stream>>>(
        S_normed, 1024, 0, 0, wk_b, 1024, 0, 0, S_k, 1024, 0, 0,
        nullptr, 0, 1024, 1, 1.0f);
    mgemm_k<2,2,4,4,0,1><<<dim3(8, 32, 1), B256, 0, stream>>>(
        S_normed, 1024, 0, 0, wv_b, 1024, 0, 0, S_v, 1024, 0, 0,
        nullptr, 0, 1024, 1, 1.0f);

    // 9. kmod[t, h*64+e] = k[t,h*64+:] @ relT[h,e,:]^T  (128x64, z=h)
    mgemm_k<4,1,2,4,0,1><<<dim3(1, 32, 16), B256, 0, stream>>>(
        S_k, 1024, 0, 64, relT, 64, 0, 4096, S_kmod, 1024, 0, 64,
        nullptr, 0, 64, 16, 1.0f);

    // 9.5 vT
    vtrans_k<<<dim3(32, 32), B256, 0, stream>>>(S_v, S_vT);

    // 10. attn logits = 0.125 * q @ kmod^T -> out.ATTN (fp32)
    mgemm_k<2,2,4,4,0,0><<<dim3(16, 16, 32), B256, 0, stream>>>(
        S_q, 1024, 2048L * 1024, 64,
        S_kmod, 1024, 2048L * 1024, 64,
        out + OUT_ATTN, TT, 16L * TT * TT, (long)TT * TT,
        nullptr, 0, 64, 16, 0.125f);

    // 11. softmax in place
    attn_softmax_k<<<dim3(BB * N_HEADS * TT), B256, 0, stream>>>(out + OUT_ATTN);

    // 12. attnout = probs(f32, converted) @ vT^T -> bf16  (128x64, z=(b,h))
    mgemm_k<4,1,2,4,1,1><<<dim3(1, 16, 32), B256, 0, stream>>>(
        out + OUT_ATTN, TT, 16L * TT * TT, (long)TT * TT,
        S_vT, 2048, 16L * 131072, 131072,
        attnout, 1024, 2048L * 1024, 64,
        nullptr, 0, 2048, 16, 1.0f);

    // 13. x2 = x + attnout @ wo^T (fp32 out F0)
    mgemm_k<2,2,4,4,0,2><<<dim3(8, 32, 1), B256, 0, stream>>>(
        attnout, 1024, 0, 0, wo_b, 1024, 0, 0, F0, 1024, 0, 0,
        x, 1024, 1024, 1, 1.0f);

    // 14. normed2 -> bf16
    rms_k<<<dim3(NTOK), B256, 0, stream>>>(F0, norm2, S_normed2, accums + 2);

    // 15. hidden = sigmoid(.@G^T)*silu(.@U^T) -> bf16
    mgateup_k<<<dim3(64, 32), B256, 0, stream>>>(S_normed2, g_b, u_b, hidden);

    // 16. x_out = x2 + hidden @ d^T -> out.X
    mgemm_k<2,2,4,4,0,2><<<dim3(8, 32, 1), B256, 0, stream>>>(
        hidden, 4096, 0, 0, d_b, 4096, 0, 0, out + OUT_X, 1024, 0, 0,
        F0, 1024, 4096, 1, 1.0f);

    // 17. scalars
    finalize_k<<<dim3(1), dim3(1), 0, stream>>>(accums, out);
}